// Round 1
// baseline (21.117 us; speedup 1.0000x reference)
//
#include <hip/hip_runtime.h>
#include <hip/hip_bf16.h>
#include <math.h>

// Problem constants (from reference setup_inputs)
#define BATCH   512          // bs * n_vars = 64 * 8
#define KP      3            // k_positive
#define KN      16           // k_negative
#define KTOT    (KP + KN)    // 19
#define PD      8192         // P * D = 64 * 128
#define INV_T   50.0f        // 1 / temperature (0.02)

#define SPLIT   8            // blocks per sample
#define CHUNK   (PD / SPLIT) // 1024 floats per block
#define THREADS 256          // 256 threads * 4 floats = 1024

__global__ __launch_bounds__(THREADS)
void agg_rebuild_kernel(const float* __restrict__ sim,
                        const float* __restrict__ p_enc,
                        const int*   __restrict__ neg_idx,
                        float*       __restrict__ out) {
    const int b    = blockIdx.x / SPLIT;   // sample index
    const int part = blockIdx.x % SPLIT;   // which chunk of the 8192 elems
    const int tid  = threadIdx.x;

    __shared__ float        s_w[KTOT];
    __shared__ const float* s_row[KTOT];

    // --- softmax over 19 temperature-scaled scores (thread 0, serial: trivial)
    if (tid == 0) {
        float v[KTOT];
        float m = -INFINITY;
        #pragma unroll
        for (int k = 0; k < KTOT; ++k) {
            v[k] = sim[(size_t)b * KTOT + k] * INV_T;
            m = fmaxf(m, v[k]);
        }
        float s = 0.0f;
        #pragma unroll
        for (int k = 0; k < KTOT; ++k) {
            v[k] = __expf(v[k] - m);
            s += v[k];
        }
        const float inv = 1.0f / s;
        #pragma unroll
        for (int k = 0; k < KTOT; ++k) s_w[k] = v[k] * inv;
    }

    // --- row base pointers: 3 positives (contiguous), 16 gathered negatives
    if (tid < KTOT) {
        int row;
        if (tid < KP) row = BATCH + b * KP + tid;
        else          row = neg_idx[(size_t)b * KN + (tid - KP)];
        s_row[tid] = p_enc + (size_t)row * PD;
    }
    __syncthreads();

    // --- weighted sum of 19 rows, one float4 per thread, fully coalesced
    const int d = part * CHUNK + tid * 4;
    float4 acc = make_float4(0.f, 0.f, 0.f, 0.f);
    #pragma unroll
    for (int k = 0; k < KTOT; ++k) {
        const float  w = s_w[k];
        const float4 x = *reinterpret_cast<const float4*>(s_row[k] + d);
        acc.x = fmaf(w, x.x, acc.x);
        acc.y = fmaf(w, x.y, acc.y);
        acc.z = fmaf(w, x.z, acc.z);
        acc.w = fmaf(w, x.w, acc.w);
    }
    *reinterpret_cast<float4*>(out + (size_t)b * PD + d) = acc;
}

extern "C" void kernel_launch(void* const* d_in, const int* in_sizes, int n_in,
                              void* d_out, int out_size, void* d_ws, size_t ws_size,
                              hipStream_t stream) {
    const float* sim     = (const float*)d_in[0];   // [B, 19]
    const float* p_enc   = (const float*)d_in[1];   // [B*(1+KP), P, D]
    const int*   neg_idx = (const int*)d_in[2];     // [B, KN]
    float*       out     = (float*)d_out;           // [B, P, D]

    dim3 grid(BATCH * SPLIT);
    dim3 block(THREADS);
    agg_rebuild_kernel<<<grid, block, 0, stream>>>(sim, p_enc, neg_idx, out);
}